// Round 4
// baseline (1205.243 us; speedup 1.0000x reference)
//
#include <hip/hip_runtime.h>
#include <hip/hip_bf16.h>

// Problem constants (fixed by the reference)
#define BSZ  64
#define ILEN 256
#define TLEN 64
#define TTOT (ILEN + TLEN)   // 320
#define IDIM 512
#define HDIM 1024
#define ODIM 128

// Round 10:
//  (a) ADAPTIVE census: (group, role) derived from measured HW_REG_XCC_ID.
//      Each block atomicAdds a per-XCD counter; first 32 on XCD x become
//      roles 0..31 of group x (pure => L2-local FAST path by construction,
//      regardless of the dispatcher's block->XCD mapping). Overflow blocks
//      deterministically fill deficit groups; those groups run the IF path.
//      Replaces the blk&7 mapping whose purity depended on round-robin
//      dispatch (suspected failing: step time matches IF latencies).
//  (b) own-flag poll elision: no lane waits on the block's OWN flag
//      (visibility RT re-paid every step). Own-block data/ring safety hold
//      by program order; the 31-producer conjunction via barrier1 is
//      unchanged (flag(t) => passed barrier1(t-1) => all flags >= t-1).
#define NBLK 256
#define NTHR 512
#define NGRP 8
#define GBLK 32          // blocks per group
#define UPB  32          // hidden units per block
#define NT   8           // n-tiles (16 gate rows each)
#define PN   132         // LDS partial pitch (floats)
#define HSLOT (BSZ * HDIM)
#define XBUFF (2 * 8 * 4 * 32)   // x-gate LDS double buffer (floats)

typedef __attribute__((ext_vector_type(8))) short short8;  // 8 x bf16
typedef __attribute__((ext_vector_type(4))) float f32x4;
typedef _Float16 half_t;

__device__ inline ushort f2bf(float f) {            // RNE float->bf16
  unsigned u = __builtin_bit_cast(unsigned, f);
  u += 0x7fffu + ((u >> 16) & 1u);
  return (ushort)(u >> 16);
}

__device__ inline float fast_sigmoid(float x) {
  float e = __expf(-x);
  return 1.0f / (1.0f + e);
}
__device__ inline float fast_tanh(float x) {
  float e = __expf(2.0f * x);
  return 1.0f - 2.0f / (1.0f + e);
}

__device__ inline void st_h_sys(ushort* p, ushort v) {   // IF path h store
  __hip_atomic_store(p, v, __ATOMIC_RELAXED, __HIP_MEMORY_SCOPE_SYSTEM);
}
__device__ inline void vm_drain() { asm volatile("s_waitcnt vmcnt(0)" ::: "memory"); }

template<bool FAST>
__device__ __forceinline__ int ldflag(const int* p) {
  if constexpr (FAST)
    return __hip_atomic_load(p, __ATOMIC_RELAXED, __HIP_MEMORY_SCOPE_AGENT);
  else
    return __hip_atomic_load(p, __ATOMIC_RELAXED, __HIP_MEMORY_SCOPE_SYSTEM);
}
template<bool FAST>
__device__ __forceinline__ void stflag(int* p, int v) {
  if constexpr (FAST)
    __hip_atomic_store(p, v, __ATOMIC_RELAXED, __HIP_MEMORY_SCOPE_AGENT);
  else
    __hip_atomic_store(p, v, __ATOMIC_RELAXED, __HIP_MEMORY_SCOPE_SYSTEM);
}

// 4x16B h loads with IN-ASM waitcnt: outputs are valid when the asm block
// ends, so consumer MFMAs carry a true data dependence.
template<bool FAST>
__device__ __forceinline__ void ld_h4(const ushort* p, short8& a0, short8& a1,
                                      short8& a2, short8& a3) {
  if constexpr (FAST)
    asm volatile("global_load_dwordx4 %0, %4, off sc0\n\t"
                 "global_load_dwordx4 %1, %4, off offset:64 sc0\n\t"
                 "global_load_dwordx4 %2, %4, off offset:128 sc0\n\t"
                 "global_load_dwordx4 %3, %4, off offset:192 sc0\n\t"
                 "s_waitcnt vmcnt(0)"
                 : "=&v"(a0), "=&v"(a1), "=&v"(a2), "=&v"(a3)
                 : "v"(p) : "memory");
  else
    asm volatile("global_load_dwordx4 %0, %4, off sc0 sc1\n\t"
                 "global_load_dwordx4 %1, %4, off offset:64 sc0 sc1\n\t"
                 "global_load_dwordx4 %2, %4, off offset:128 sc0 sc1\n\t"
                 "global_load_dwordx4 %3, %4, off offset:192 sc0 sc1\n\t"
                 "s_waitcnt vmcnt(0)"
                 : "=&v"(a0), "=&v"(a1), "=&v"(a2), "=&v"(a3)
                 : "v"(p) : "memory");
}

__device__ __forceinline__ void gload_lds16(const ushort* g, ushort* l) {
  __builtin_amdgcn_global_load_lds(
      (const __attribute__((address_space(1))) unsigned int*)g,
      (__attribute__((address_space(3))) unsigned int*)l, 16, 0, 0);
}

// ---------------- prep: bf16 conversions, w_hh swizzle, zero state ----------------
// whh_sw frag index f = (((role*8 + wv)*4 + c)*8 + nt)*64 + lane; 8 bf16 each.
__global__ void prep_kernel(const float* __restrict__ inp, const float* __restrict__ clfw,
                            const float* __restrict__ w_ih, const float* __restrict__ w_hh,
                            ushort* __restrict__ inp_bf, ushort* __restrict__ clfw_bf,
                            ushort* __restrict__ wih_bf, ushort* __restrict__ whh_sw,
                            ushort* __restrict__ hbuf, int* __restrict__ bar,
                            int* __restrict__ hand)
{
  const long np  = (long)gridDim.x * blockDim.x;
  const long tid = (long)blockIdx.x * blockDim.x + threadIdx.x;

  const float4* in4 = (const float4*)inp;
  ushort4* ob4 = (ushort4*)inp_bf;
  for (long i = tid; i < (long)BSZ * ILEN * IDIM / 4; i += np) {
    float4 v = in4[i];
    ushort4 o; o.x = f2bf(v.x); o.y = f2bf(v.y); o.z = f2bf(v.z); o.w = f2bf(v.w);
    ob4[i] = o;
  }
  const float4* cw4 = (const float4*)clfw;
  ushort4* cb4 = (ushort4*)clfw_bf;
  for (long i = tid; i < (long)ODIM * HDIM / 4; i += np) {
    float4 v = cw4[i];
    ushort4 o; o.x = f2bf(v.x); o.y = f2bf(v.y); o.z = f2bf(v.z); o.w = f2bf(v.w);
    cb4[i] = o;
  }
  const float4* wi4 = (const float4*)w_ih;
  ushort4* wb4 = (ushort4*)wih_bf;
  for (long i = tid; i < (long)4 * HDIM * IDIM / 4; i += np) {
    float4 v = wi4[i];
    ushort4 o; o.x = f2bf(v.x); o.y = f2bf(v.y); o.z = f2bf(v.z); o.w = f2bf(v.w);
    wb4[i] = o;
  }
  // w_hh swizzle: 32role x 8wv x 4c x 8nt x 64lane fragments of 8 (vectorized)
  for (long f = tid; f < 32L * 8 * 4 * 8 * 64; f += np) {   // 524288
    const int lane = (int)(f & 63);
    const int nt   = (int)((f >> 6) & 7);
    const int c    = (int)((f >> 9) & 3);
    const int wv   = (int)((f >> 11) & 7);
    const int r    = (int)(f >> 14);                // role 0..31
    const int nl   = nt * 16 + (lane & 15);         // 0..127
    const long grow = (long)(nl >> 5) * HDIM + r * UPB + (nl & 31);
    const int k = wv * 128 + c * 32 + (lane >> 4) * 8;
    const float* src = w_hh + grow * HDIM + k;
    const float4 s0 = *(const float4*)(src);
    const float4 s1 = *(const float4*)(src + 4);
    ushort4 d0, d1;
    d0.x = f2bf(s0.x); d0.y = f2bf(s0.y); d0.z = f2bf(s0.z); d0.w = f2bf(s0.w);
    d1.x = f2bf(s1.x); d1.y = f2bf(s1.y); d1.z = f2bf(s1.z); d1.w = f2bf(s1.w);
    ushort* dst = whh_sw + f * 8;
    *(ushort4*)(dst)     = d0;
    *(ushort4*)(dst + 4) = d1;
  }
  // zero h ring via the system path (memory-side => visible to both modes)
  for (long i = tid; i < (long)4 * HSLOT; i += np)
    st_h_sys(hbuf + i, 0);
  for (long i = tid; i < NBLK * 32; i += np)
    __hip_atomic_store(bar + (int)i, 0, __ATOMIC_RELAXED, __HIP_MEMORY_SCOPE_SYSTEM);
  for (long i = tid; i < 256; i += np)
    __hip_atomic_store(hand + (int)i, 0, __ATOMIC_RELAXED, __HIP_MEMORY_SCOPE_SYSTEM);
}

// ---------------- xproj GEMM (m97 structure): xp[m][n] = inp[m] . w_ih[n] ----------
__global__ __launch_bounds__(256, 2) void xproj_kernel(
    const ushort* __restrict__ inp_bf, const ushort* __restrict__ wih_bf,
    half_t* __restrict__ xproj)
{
  __shared__ ushort As[128 * 32];   // [row][32k] 64B rows, linear (gload_lds dest)
  __shared__ ushort Bs[128 * 32];

  const int tid = threadIdx.x;
  const int wv = tid >> 6, lane = tid & 63, l15 = lane & 15, quad = lane >> 4;
  const int bs = (blockIdx.x & 7) * 512 + (blockIdx.x >> 3);  // XCD swizzle
  const long mb = (long)(bs >> 5) * 128;    // 128 m-tiles
  const long nb = (long)(bs & 31) * 128;    // 32 n-tiles
  const int wr = wv >> 1, wc = wv & 1;

  // staging: wave wv stages rows [wv*32, wv*32+32) of A and B, 2 chunks of 16
  const int srow = wv * 32 + (lane >> 2);
  const int scol = (lane & 3) * 8;
  const ushort* ga = inp_bf + (mb + srow) * IDIM + scol;
  const ushort* gb = wih_bf + (nb + srow) * IDIM + scol;
  ushort* const la = As + wv * 32 * 32;     // wave-uniform LDS bases
  ushort* const lb = Bs + wv * 32 * 32;

  f32x4 acc[4][4];
  #pragma unroll
  for (int mt = 0; mt < 4; ++mt)
    #pragma unroll
    for (int nt = 0; nt < 4; ++nt)
      #pragma unroll
      for (int r = 0; r < 4; ++r) acc[mt][nt][r] = 0.0f;

  for (int kc = 0; kc < IDIM / 32; ++kc) {
    const int k = kc * 32;
    gload_lds16(ga + k,             la);
    gload_lds16(ga + 16 * IDIM + k, la + 16 * 32);
    gload_lds16(gb + k,             lb);
    gload_lds16(gb + 16 * IDIM + k, lb + 16 * 32);
    asm volatile("s_waitcnt vmcnt(0)" ::: "memory");
    __syncthreads();

    short8 af[4], bf[4];
    #pragma unroll
    for (int mt = 0; mt < 4; ++mt)
      af[mt] = *(const short8*)(As + (wr * 64 + mt * 16 + l15) * 32 + quad * 8);
    #pragma unroll
    for (int nt = 0; nt < 4; ++nt)
      bf[nt] = *(const short8*)(Bs + (wc * 64 + nt * 16 + l15) * 32 + quad * 8);
    #pragma unroll
    for (int mt = 0; mt < 4; ++mt)
      #pragma unroll
      for (int nt = 0; nt < 4; ++nt)
        acc[mt][nt] = __builtin_amdgcn_mfma_f32_16x16x32_bf16(af[mt], bf[nt],
                                                              acc[mt][nt], 0, 0, 0);
    __syncthreads();
  }

  #pragma unroll
  for (int mt = 0; mt < 4; ++mt)
    #pragma unroll
    for (int nt = 0; nt < 4; ++nt)
      #pragma unroll
      for (int r = 0; r < 4; ++r) {
        const long m = mb + wr * 64 + mt * 16 + quad * 4 + r;
        const long n = nb + wc * 64 + nt * 16 + l15;
        xproj[m * (4 * HDIM) + n] = (half_t)acc[mt][nt][r];
      }
}

// ---------------- persistent LSTM body (templated on sync path) ----------------
// MFMA 16x16x32 bf16 layouts (validated rounds 1-6):
//   A frag: A[m = lane&15][k = (lane>>4)*8 + j]
//   B frag: rows W[n][k], n = lane&15, k = (lane>>4)*8 + j
//   C/D:    col(n) = lane&15, row(m) = (lane>>4)*4 + reg
template<bool FAST>
__device__ __forceinline__ void lstm_body(
    const ushort* __restrict__ whh_sw, const half_t* __restrict__ xproj,
    const float* __restrict__ bias, ushort* __restrict__ hbuf,
    ushort* __restrict__ hs_bf, int* __restrict__ flags,
    const int g, const int role)
{
  extern __shared__ float part[];          // [8 waves][16 m][PN] (67.6 KB)
  float* const xbuf = part + 8 * 16 * PN;  // [2][8 em][4 gate][32 uu] (+8 KB)

  const int tid  = threadIdx.x;
  const int wv   = tid >> 6;        // wave 0..7 (K=1024 split 8 ways)
  const int lane = tid & 63;
  const int l15  = lane & 15;
  const int quad = lane >> 4;
  const int j0u  = role * UPB;      // first hidden unit owned
  const int m0   = g * 8;           // first batch row of this group

  // ---- 32 weight fragments per wave (128 regs; AGPR-resident) ----
  short8 wfrag[4][NT];
  {
    const ushort* wp = whh_sw + (long)(role * 8 + wv) * 16384 + lane * 8;
    #pragma unroll
    for (int c = 0; c < 4; ++c)
      #pragma unroll
      for (int nt = 0; nt < NT; ++nt)
        wfrag[c][nt] = *(const short8*)(wp + (c * NT + nt) * 512);
  }
  #pragma unroll
  for (int c = 0; c < 4; ++c)
    #pragma unroll
    for (int nt = 0; nt < NT; ++nt)
      asm volatile("" : "+v"(wfrag[c][nt]));

  // ---- cell mapping: threads 0..255 own (batch em 0..7, unit uu 0..31) ----
  const int em = tid >> 5;
  const int uu = tid & 31;
  float bi = 0, bf_ = 0, bg = 0, bo = 0;
  if (tid < 256) {
    bi  = bias[0 * HDIM + j0u + uu];
    bf_ = bias[1 * HDIM + j0u + uu];
    bg  = bias[2 * HDIM + j0u + uu];
    bo  = bias[3 * HDIM + j0u + uu];
  }
  float cst = 0.0f;

  // ---- waves 4-7: x-gate staging mapping (lane4 -> em4, gate g4, 4 units) ----
  const int lane4 = (tid - 256) & 255;     // valid when tid>=256; benign otherwise
  const int em4 = lane4 >> 5;
  const int g4  = (lane4 >> 3) & 3;
  const int u0  = (lane4 & 7) * 4;
  const half_t* xsrc = xproj + (long)(m0 + em4) * ILEN * (4 * HDIM)
                       + g4 * HDIM + j0u + u0;

  // ---- sync: wave wv's chunk c comes from role 4*wv + c.
  //      Own-role lane contributes constant-true (data + ring safety for
  //      the own block hold by program order: h stores drained before own
  //      flag store, which precedes this poll). ----
  int* const fmine = flags + (g * GBLK + role) * 32;
  const int prole = wv * 4 + (lane & 3);              // this lane's producer
  const bool pollme = (lane < 4) && (prole != role);
  const int* const myfp = flags + (g * GBLK + prole) * 32;

  // ---- pre-stage x(0) into xbuf slot 0 (ordered by barrier1 of t=0) ----
  if (tid >= 256) {
    ushort4 x0 = *(const ushort4*)xsrc;
    float4 v;
    v.x = (float)__builtin_bit_cast(half_t, (ushort)x0.x);
    v.y = (float)__builtin_bit_cast(half_t, (ushort)x0.y);
    v.z = (float)__builtin_bit_cast(half_t, (ushort)x0.z);
    v.w = (float)__builtin_bit_cast(half_t, (ushort)x0.w);
    *(float4*)(xbuf + 0 * 1024 + em4 * 128 + g4 * 32 + u0) = v;
  }

  for (int t = 0; t < TTOT; ++t) {
    const ushort* __restrict__ hsrc = hbuf + (t & 3) * HSLOT;
    ushort* __restrict__ hdst = hbuf + ((t + 1) & 3) * HSLOT;

    // ---- poll: lanes 0..3 watch this wave's 4 producer roles (own role
    //      elided -> no wave waits on the own-flag visibility RT) ----
    for (;;) {
      int v = 0x7fffffff;
      if (pollme) v = ldflag<FAST>(myfp);
      if (__all(v >= t)) break;
      __builtin_amdgcn_s_sleep(1);
    }

    // ---- h loads for this wave's K slice (in-asm waitcnt) ----
    const ushort* hb = hsrc + (long)(m0 + (l15 & 7)) * HDIM + wv * 128 + quad * 8;
    short8 ah0, ah1, ah2, ah3;
    ld_h4<FAST>(hb, ah0, ah1, ah2, ah3);

    // ---- waves 4-7: issue x(t+1) load NOW (no wait); completes after
    //      barrier1, hidden under waves 0-3's reduce window ----
    ushort4 xr;
    const bool havex = (tid >= 256) && (t + 1 < ILEN);
    if (havex) {
      const ushort* xp = (const ushort*)(xsrc + (long)(t + 1) * (4 * HDIM));
      asm volatile("global_load_dwordx2 %0, %1, off"
                   : "=&v"(xr) : "v"(xp) : "memory");
    }

    f32x4 acc[NT];
    #pragma unroll
    for (int nt = 0; nt < NT; ++nt)
      #pragma unroll
      for (int r = 0; r < 4; ++r) acc[nt][r] = 0.0f;

    #pragma unroll
    for (int nt = 0; nt < NT; ++nt)
      acc[nt] = __builtin_amdgcn_mfma_f32_16x16x32_bf16(ah0, wfrag[0][nt], acc[nt], 0, 0, 0);
    #pragma unroll
    for (int nt = 0; nt < NT; ++nt)
      acc[nt] = __builtin_amdgcn_mfma_f32_16x16x32_bf16(ah1, wfrag[1][nt], acc[nt], 0, 0, 0);
    #pragma unroll
    for (int nt = 0; nt < NT; ++nt)
      acc[nt] = __builtin_amdgcn_mfma_f32_16x16x32_bf16(ah2, wfrag[2][nt], acc[nt], 0, 0, 0);
    #pragma unroll
    for (int nt = 0; nt < NT; ++nt)
      acc[nt] = __builtin_amdgcn_mfma_f32_16x16x32_bf16(ah3, wfrag[3][nt], acc[nt], 0, 0, 0);

    // ---- partials to LDS (col = n, lane-stride 1 => conflict-free) ----
    if (quad < 2) {
      #pragma unroll
      for (int nt = 0; nt < NT; ++nt)
        #pragma unroll
        for (int r = 0; r < 4; ++r)
          part[(wv * 16 + quad * 4 + r) * PN + nt * 16 + l15] = acc[nt][r];
    }

    // ---- barrier1: RAW (lgkm drain only); waves 4-7 x load stays in
    //      flight. All waves passed polls => all group flags >= t (31
    //      via flags + own via program order) => ring slot safe. ----
    asm volatile("s_waitcnt lgkmcnt(0)" ::: "memory");
    __builtin_amdgcn_s_barrier();

    ushort h16 = 0;
    if (tid < 256) {
      // x gates from LDS (staged last step by waves 4-7); zeros when padded
      float xi = 0, xf = 0, xg = 0, xo = 0;
      if (t < ILEN) {
        const float* xb = xbuf + (t & 1) * 1024 + em * 128 + uu;
        xi = xb[0]; xf = xb[32]; xg = xb[64]; xo = xb[96];
      }
      float gi = bi + xi, gf = bf_ + xf, gg = bg + xg, go = bo + xo;
      #pragma unroll
      for (int w = 0; w < 8; ++w) {
        const float* pw = part + (w * 16 + em) * PN;
        gi += pw[0 * 32 + uu];
        gf += pw[1 * 32 + uu];
        gg += pw[2 * 32 + uu];
        go += pw[3 * 32 + uu];
      }
      const float si = fast_sigmoid(gi);
      const float sf = fast_sigmoid(gf);
      const float tg = fast_tanh(gg);
      const float so = fast_sigmoid(go);
      cst = sf * cst + si * tg;
      const float h = so * fast_tanh(cst);
      h16 = f2bf(h);
      if constexpr (FAST)
        hdst[(long)(m0 + em) * HDIM + j0u + uu] = h16;      // L2-local (XCD)
      else
        st_h_sys(hdst + (long)(m0 + em) * HDIM + j0u + uu, h16);  // IF
    } else if (havex) {
      // complete x(t+1): only this wave's single load is outstanding
      asm volatile("s_waitcnt vmcnt(0)" ::: "memory");
      float4 v;
      v.x = (float)__builtin_bit_cast(half_t, (ushort)xr.x);
      v.y = (float)__builtin_bit_cast(half_t, (ushort)xr.y);
      v.z = (float)__builtin_bit_cast(half_t, (ushort)xr.z);
      v.w = (float)__builtin_bit_cast(half_t, (ushort)xr.w);
      *(float4*)(xbuf + ((t + 1) & 1) * 1024 + em4 * 128 + g4 * 32 + u0) = v;
    }

    // ---- publish: own h stores complete before flag store ----
    vm_drain();
    __syncthreads();
    if (tid == 0) stflag<FAST>(fmine, t + 1);   // monotonic, no ABA

    // ---- off-critical-path work after publish ----
    if (tid < 256 && t >= ILEN)
      hs_bf[((long)(m0 + em) * TLEN + (t - ILEN)) * HDIM + j0u + uu] = h16;
  }
}

__global__ __launch_bounds__(NTHR, 2) void lstm_kernel(
    const ushort* __restrict__ whh_sw, const half_t* __restrict__ xproj,
    const float* __restrict__ bias,
    ushort* __restrict__ hbuf, ushort* __restrict__ hs_bf,
    int* __restrict__ flags, int* __restrict__ hand)
{
  // ---- adaptive census: (g, role) from the MEASURED XCD. hand[0..7] =
  //      per-XCD rank counters; hand[8] = registered; hand[9] = overflow.
  //      First GBLK blocks on XCD x serve group x (pure by construction);
  //      overflow blocks deterministically fill deficit groups (IF path).
  __shared__ int s_g, s_role, s_fast;
  if (threadIdx.x == 0) {
    int xcd = 0;
    asm volatile("s_getreg_b32 %0, hwreg(HW_REG_XCC_ID)" : "=s"(xcd));
    xcd &= 7;
    const int idx = __hip_atomic_fetch_add(&hand[xcd], 1,
                        __ATOMIC_RELAXED, __HIP_MEMORY_SCOPE_SYSTEM);
    int ov = -1;
    if (idx >= GBLK)
      ov = __hip_atomic_fetch_add(&hand[9], 1,
               __ATOMIC_RELAXED, __HIP_MEMORY_SCOPE_SYSTEM);
    __hip_atomic_fetch_add(&hand[8], 1,
        __ATOMIC_RELEASE, __HIP_MEMORY_SCOPE_SYSTEM);
    while (__hip_atomic_load(&hand[8], __ATOMIC_ACQUIRE,
                             __HIP_MEMORY_SCOPE_SYSTEM) < NBLK)
      __builtin_amdgcn_s_sleep(2);
    int cnt[8];
    #pragma unroll
    for (int x = 0; x < 8; ++x)
      cnt[x] = __hip_atomic_load(&hand[x], __ATOMIC_RELAXED,
                                 __HIP_MEMORY_SCOPE_SYSTEM);
    int g, role;
    if (idx < GBLK) {
      g = xcd; role = idx;
    } else {
      int r = ov; g = 0; role = 0;
      for (int x = 0; x < 8; ++x) {
        const int have = cnt[x] < GBLK ? cnt[x] : GBLK;
        const int def = GBLK - have;
        if (r < def) { g = x; role = have + r; break; }
        r -= def;
      }
    }
    s_g = g; s_role = role; s_fast = (cnt[g] >= GBLK) ? 1 : 0;
  }
  __syncthreads();
  const int g = s_g, role = s_role;
  const bool fast = s_fast != 0;

  if (fast) lstm_body<true >(whh_sw, xproj, bias, hbuf, hs_bf, flags, g, role);
  else      lstm_body<false>(whh_sw, xproj, bias, hbuf, hs_bf, flags, g, role);
}

// ---------------- classifier: sigmoid(hs @ clf_w^T + clf_b) ----------------
__global__ __launch_bounds__(256, 1) void clf_kernel(
    const ushort* __restrict__ hs_bf, const ushort* __restrict__ clfw_bf,
    const float* __restrict__ clf_b, float* __restrict__ out)
{
  const int tid = threadIdx.x;
  const int wv = tid >> 6, lane = tid & 63, l15 = lane & 15, quad = lane >> 4;
  const int m0 = blockIdx.x * 64 + wv * 16;   // rows = (b, tt) pairs, 4096 total

  f32x4 acc[8];
  #pragma unroll
  for (int nt = 0; nt < 8; ++nt)
    #pragma unroll
    for (int r = 0; r < 4; ++r) acc[nt][r] = 0.0f;

  for (int kc = 0; kc < HDIM / 32; ++kc) {
    const int k = kc * 32 + quad * 8;
    short8 a = *(const short8*)(hs_bf + (long)(m0 + l15) * HDIM + k);
    #pragma unroll
    for (int nt = 0; nt < 8; ++nt) {
      short8 b = *(const short8*)(clfw_bf + (long)(nt * 16 + l15) * HDIM + k);
      acc[nt] = __builtin_amdgcn_mfma_f32_16x16x32_bf16(a, b, acc[nt], 0, 0, 0);
    }
  }
  #pragma unroll
  for (int nt = 0; nt < 8; ++nt) {
    const int n = nt * 16 + l15;
    const float bn = clf_b[n];
    #pragma unroll
    for (int r = 0; r < 4; ++r) {
      const int m = m0 + quad * 4 + r;
      out[(long)m * ODIM + n] = fast_sigmoid(acc[nt][r] + bn);
    }
  }
}

// ---------------- launch ----------------
extern "C" void kernel_launch(void* const* d_in, const int* in_sizes, int n_in,
                              void* d_out, int out_size, void* d_ws, size_t ws_size,
                              hipStream_t stream) {
  const float* inp   = (const float*)d_in[0];
  // d_in[1] = tlen scalar (fixed = 64 for this problem)
  const float* w_ih  = (const float*)d_in[2];
  const float* w_hh  = (const float*)d_in[3];
  const float* bias  = (const float*)d_in[4];
  const float* clf_w = (const float*)d_in[5];
  const float* clf_b = (const float*)d_in[6];
  float* out = (float*)d_out;

  // ws layout (bytes): total ~172.8 MB
  char* ws = (char*)d_ws;
  ushort* inp_bf  = (ushort*)(ws + 0);          // 16,777,216
  ushort* wih_bf  = (ushort*)(ws + 16777216);   //  4,194,304
  ushort* whh_sw  = (ushort*)(ws + 20971520);   //  8,388,608 (swizzled w_hh)
  ushort* clfw_bf = (ushort*)(ws + 29360128);   //    262,144
  ushort* hbuf    = (ushort*)(ws + 29622272);   //    524,288 (4-slot h ring)
  ushort* hs_bf   = (ushort*)(ws + 30146560);   //  8,388,608 (last-64-step h)
  int*    bar     = (int*)   (ws + 38535168);   //     32,768 (per-block flags)
  int*    hand    = (int*)   (ws + 38567936);   //      1,024 (XCD census)
  half_t* xproj   = (half_t*)(ws + 38568960);   // 134,217,728 (fp16 x-projection)

  prep_kernel<<<4096, 256, 0, stream>>>(inp, clf_w, w_ih, w_hh,
                                        inp_bf, clfw_bf, wih_bf, whh_sw,
                                        hbuf, bar, hand);
  xproj_kernel<<<4096, 256, 0, stream>>>(inp_bf, wih_bf, xproj);
  lstm_kernel<<<NBLK, NTHR, (8 * 16 * PN + XBUFF) * 4, stream>>>(
      whh_sw, xproj, bias, hbuf, hs_bf, bar, hand);
  clf_kernel<<<64, 256, 0, stream>>>(hs_bf, clfw_bf, clf_b, out);
}

// Round 6
// 1063.876 us; speedup vs baseline: 1.1329x; 1.1329x over previous
//
#include <hip/hip_runtime.h>
#include <hip/hip_bf16.h>

// Problem constants (fixed by the reference)
#define BSZ  64
#define ILEN 256
#define TLEN 64
#define TTOT (ILEN + TLEN)   // 320
#define IDIM 512
#define HDIM 1024
#define ODIM 128

// Round 12: LSTM reverted VERBATIM to round-9 (last passing: 875us lstm,
// 1066us total). Round-11's inline-asm pipelined poll is WITHDRAWN: it
// livelocked around t~ILEN+3 (no-sleep sc0sc1 probe flood starving flag
// visibility at IF; partial hs_bf + killed launch). This round's only
// change is intra-block: xproj becomes 2-phase double-buffered LDS
// (stage K-tile k+1 during compute of k; one vmcnt(0)+barrier per step).
#define NBLK 256
#define NTHR 512
#define NGRP 8
#define GBLK 32          // blocks per group
#define UPB  32          // hidden units per block
#define NT   8           // n-tiles (16 gate rows each)
#define PN   132         // LDS partial pitch (floats)
#define HSLOT (BSZ * HDIM)
#define XBUFF (2 * 8 * 4 * 32)   // x-gate LDS double buffer (floats)

typedef __attribute__((ext_vector_type(8))) short short8;  // 8 x bf16
typedef __attribute__((ext_vector_type(4))) float f32x4;
typedef _Float16 half_t;

__device__ inline ushort f2bf(float f) {            // RNE float->bf16
  unsigned u = __builtin_bit_cast(unsigned, f);
  u += 0x7fffu + ((u >> 16) & 1u);
  return (ushort)(u >> 16);
}

__device__ inline float fast_sigmoid(float x) {
  float e = __expf(-x);
  return 1.0f / (1.0f + e);
}
__device__ inline float fast_tanh(float x) {
  float e = __expf(2.0f * x);
  return 1.0f - 2.0f / (1.0f + e);
}

__device__ inline void st_h_sys(ushort* p, ushort v) {   // IF path h store
  __hip_atomic_store(p, v, __ATOMIC_RELAXED, __HIP_MEMORY_SCOPE_SYSTEM);
}
__device__ inline void vm_drain() { asm volatile("s_waitcnt vmcnt(0)" ::: "memory"); }

template<bool FAST>
__device__ __forceinline__ int ldflag(const int* p) {
  if constexpr (FAST)
    return __hip_atomic_load(p, __ATOMIC_RELAXED, __HIP_MEMORY_SCOPE_AGENT);
  else
    return __hip_atomic_load(p, __ATOMIC_RELAXED, __HIP_MEMORY_SCOPE_SYSTEM);
}
template<bool FAST>
__device__ __forceinline__ void stflag(int* p, int v) {
  if constexpr (FAST)
    __hip_atomic_store(p, v, __ATOMIC_RELAXED, __HIP_MEMORY_SCOPE_AGENT);
  else
    __hip_atomic_store(p, v, __ATOMIC_RELAXED, __HIP_MEMORY_SCOPE_SYSTEM);
}

// 4x16B h loads with IN-ASM waitcnt: outputs are valid when the asm block
// ends, so consumer MFMAs carry a true data dependence.
template<bool FAST>
__device__ __forceinline__ void ld_h4(const ushort* p, short8& a0, short8& a1,
                                      short8& a2, short8& a3) {
  if constexpr (FAST)
    asm volatile("global_load_dwordx4 %0, %4, off sc0\n\t"
                 "global_load_dwordx4 %1, %4, off offset:64 sc0\n\t"
                 "global_load_dwordx4 %2, %4, off offset:128 sc0\n\t"
                 "global_load_dwordx4 %3, %4, off offset:192 sc0\n\t"
                 "s_waitcnt vmcnt(0)"
                 : "=&v"(a0), "=&v"(a1), "=&v"(a2), "=&v"(a3)
                 : "v"(p) : "memory");
  else
    asm volatile("global_load_dwordx4 %0, %4, off sc0 sc1\n\t"
                 "global_load_dwordx4 %1, %4, off offset:64 sc0 sc1\n\t"
                 "global_load_dwordx4 %2, %4, off offset:128 sc0 sc1\n\t"
                 "global_load_dwordx4 %3, %4, off offset:192 sc0 sc1\n\t"
                 "s_waitcnt vmcnt(0)"
                 : "=&v"(a0), "=&v"(a1), "=&v"(a2), "=&v"(a3)
                 : "v"(p) : "memory");
}

__device__ __forceinline__ void gload_lds16(const ushort* g, ushort* l) {
  __builtin_amdgcn_global_load_lds(
      (const __attribute__((address_space(1))) unsigned int*)g,
      (__attribute__((address_space(3))) unsigned int*)l, 16, 0, 0);
}

// ---------------- prep: bf16 conversions, w_hh swizzle, zero state ----------------
// whh_sw frag index f = (((role*8 + wv)*4 + c)*8 + nt)*64 + lane; 8 bf16 each.
__global__ void prep_kernel(const float* __restrict__ inp, const float* __restrict__ clfw,
                            const float* __restrict__ w_ih, const float* __restrict__ w_hh,
                            ushort* __restrict__ inp_bf, ushort* __restrict__ clfw_bf,
                            ushort* __restrict__ wih_bf, ushort* __restrict__ whh_sw,
                            ushort* __restrict__ hbuf, int* __restrict__ bar,
                            int* __restrict__ hand)
{
  const long np  = (long)gridDim.x * blockDim.x;
  const long tid = (long)blockIdx.x * blockDim.x + threadIdx.x;

  const float4* in4 = (const float4*)inp;
  ushort4* ob4 = (ushort4*)inp_bf;
  for (long i = tid; i < (long)BSZ * ILEN * IDIM / 4; i += np) {
    float4 v = in4[i];
    ushort4 o; o.x = f2bf(v.x); o.y = f2bf(v.y); o.z = f2bf(v.z); o.w = f2bf(v.w);
    ob4[i] = o;
  }
  const float4* cw4 = (const float4*)clfw;
  ushort4* cb4 = (ushort4*)clfw_bf;
  for (long i = tid; i < (long)ODIM * HDIM / 4; i += np) {
    float4 v = cw4[i];
    ushort4 o; o.x = f2bf(v.x); o.y = f2bf(v.y); o.z = f2bf(v.z); o.w = f2bf(v.w);
    cb4[i] = o;
  }
  const float4* wi4 = (const float4*)w_ih;
  ushort4* wb4 = (ushort4*)wih_bf;
  for (long i = tid; i < (long)4 * HDIM * IDIM / 4; i += np) {
    float4 v = wi4[i];
    ushort4 o; o.x = f2bf(v.x); o.y = f2bf(v.y); o.z = f2bf(v.z); o.w = f2bf(v.w);
    wb4[i] = o;
  }
  // w_hh swizzle: 32role x 8wv x 4c x 8nt x 64lane fragments of 8 (vectorized)
  for (long f = tid; f < 32L * 8 * 4 * 8 * 64; f += np) {   // 524288
    const int lane = (int)(f & 63);
    const int nt   = (int)((f >> 6) & 7);
    const int c    = (int)((f >> 9) & 3);
    const int wv   = (int)((f >> 11) & 7);
    const int r    = (int)(f >> 14);                // role 0..31
    const int nl   = nt * 16 + (lane & 15);         // 0..127
    const long grow = (long)(nl >> 5) * HDIM + r * UPB + (nl & 31);
    const int k = wv * 128 + c * 32 + (lane >> 4) * 8;
    const float* src = w_hh + grow * HDIM + k;
    const float4 s0 = *(const float4*)(src);
    const float4 s1 = *(const float4*)(src + 4);
    ushort4 d0, d1;
    d0.x = f2bf(s0.x); d0.y = f2bf(s0.y); d0.z = f2bf(s0.z); d0.w = f2bf(s0.w);
    d1.x = f2bf(s1.x); d1.y = f2bf(s1.y); d1.z = f2bf(s1.z); d1.w = f2bf(s1.w);
    ushort* dst = whh_sw + f * 8;
    *(ushort4*)(dst)     = d0;
    *(ushort4*)(dst + 4) = d1;
  }
  // zero h ring via the system path (memory-side => visible to both modes)
  for (long i = tid; i < (long)4 * HSLOT; i += np)
    st_h_sys(hbuf + i, 0);
  for (long i = tid; i < NBLK * 32; i += np)
    __hip_atomic_store(bar + (int)i, 0, __ATOMIC_RELAXED, __HIP_MEMORY_SCOPE_SYSTEM);
  for (long i = tid; i < 256; i += np)
    __hip_atomic_store(hand + (int)i, 0, __ATOMIC_RELAXED, __HIP_MEMORY_SCOPE_SYSTEM);
}

// ---------------- xproj GEMM: 2-phase double-buffered (T3 minimum recipe) ----------
// 128x128 tile, BK=32, 4 waves (2x2 of 64x64), global_load_lds width-16,
// XCD swizzle. Stage tile kc+1 into buf^1 while computing tile kc from buf;
// one vmcnt(0)+barrier per K-step. Accumulation order unchanged.
__global__ __launch_bounds__(256, 2) void xproj_kernel(
    const ushort* __restrict__ inp_bf, const ushort* __restrict__ wih_bf,
    half_t* __restrict__ xproj)
{
  __shared__ ushort As[2][128 * 32];   // [buf][row][32k], linear (gload_lds dest)
  __shared__ ushort Bs[2][128 * 32];

  const int tid = threadIdx.x;
  const int wv = tid >> 6, lane = tid & 63, l15 = lane & 15, quad = lane >> 4;
  const int bs = (blockIdx.x & 7) * 512 + (blockIdx.x >> 3);  // XCD swizzle
  const long mb = (long)(bs >> 5) * 128;    // 128 m-tiles
  const long nb = (long)(bs & 31) * 128;    // 32 n-tiles
  const int wr = wv >> 1, wc = wv & 1;

  // staging: wave wv stages rows [wv*32, wv*32+32) of A and B, 2 chunks of 16
  const int srow = wv * 32 + (lane >> 2);
  const int scol = (lane & 3) * 8;
  const ushort* ga = inp_bf + (mb + srow) * IDIM + scol;
  const ushort* gb = wih_bf + (nb + srow) * IDIM + scol;
  const int lofs = wv * 32 * 32;            // wave-uniform LDS offset

  f32x4 acc[4][4];
  #pragma unroll
  for (int mt = 0; mt < 4; ++mt)
    #pragma unroll
    for (int nt = 0; nt < 4; ++nt)
      #pragma unroll
      for (int r = 0; r < 4; ++r) acc[mt][nt][r] = 0.0f;

  // prologue: stage tile 0 into buf 0
  {
    gload_lds16(ga,              &As[0][lofs]);
    gload_lds16(ga + 16 * IDIM,  &As[0][lofs + 16 * 32]);
    gload_lds16(gb,              &Bs[0][lofs]);
    gload_lds16(gb + 16 * IDIM,  &Bs[0][lofs + 16 * 32]);
    asm volatile("s_waitcnt vmcnt(0)" ::: "memory");
    __syncthreads();
  }

  const int NK = IDIM / 32;   // 16
  for (int kc = 0; kc < NK; ++kc) {
    const int cur = kc & 1;
    if (kc + 1 < NK) {         // stage next tile into the other buffer
      const int k = (kc + 1) * 32;
      gload_lds16(ga + k,             &As[cur ^ 1][lofs]);
      gload_lds16(ga + 16 * IDIM + k, &As[cur ^ 1][lofs + 16 * 32]);
      gload_lds16(gb + k,             &Bs[cur ^ 1][lofs]);
      gload_lds16(gb + 16 * IDIM + k, &Bs[cur ^ 1][lofs + 16 * 32]);
    }

    short8 af[4], bf4[4];
    #pragma unroll
    for (int mt = 0; mt < 4; ++mt)
      af[mt] = *(const short8*)(&As[cur][(wr * 64 + mt * 16 + l15) * 32 + quad * 8]);
    #pragma unroll
    for (int nt = 0; nt < 4; ++nt)
      bf4[nt] = *(const short8*)(&Bs[cur][(wc * 64 + nt * 16 + l15) * 32 + quad * 8]);
    #pragma unroll
    for (int mt = 0; mt < 4; ++mt)
      #pragma unroll
      for (int nt = 0; nt < 4; ++nt)
        acc[mt][nt] = __builtin_amdgcn_mfma_f32_16x16x32_bf16(af[mt], bf4[nt],
                                                              acc[mt][nt], 0, 0, 0);
    if (kc + 1 < NK)
      asm volatile("s_waitcnt vmcnt(0)" ::: "memory");  // next buffer staged
    __syncthreads();   // ds_reads of cur drained (compiler lgkmcnt) + staging visible
  }

  #pragma unroll
  for (int mt = 0; mt < 4; ++mt)
    #pragma unroll
    for (int nt = 0; nt < 4; ++nt)
      #pragma unroll
      for (int r = 0; r < 4; ++r) {
        const long m = mb + wr * 64 + mt * 16 + quad * 4 + r;
        const long n = nb + wc * 64 + nt * 16 + l15;
        xproj[m * (4 * HDIM) + n] = (half_t)acc[mt][nt][r];
      }
}

// ---------------- persistent LSTM body (round-9 verbatim) ----------------
// MFMA 16x16x32 bf16 layouts (validated rounds 1-6):
//   A frag: A[m = lane&15][k = (lane>>4)*8 + j]
//   B frag: rows W[n][k], n = lane&15, k = (lane>>4)*8 + j
//   C/D:    col(n) = lane&15, row(m) = (lane>>4)*4 + reg
template<bool FAST>
__device__ __forceinline__ void lstm_body(
    const ushort* __restrict__ whh_sw, const half_t* __restrict__ xproj,
    const float* __restrict__ bias, ushort* __restrict__ hbuf,
    ushort* __restrict__ hs_bf, int* __restrict__ flags)
{
  extern __shared__ float part[];          // [8 waves][16 m][PN] (67.6 KB)
  float* const xbuf = part + 8 * 16 * PN;  // [2][8 em][4 gate][32 uu] (+8 KB)

  const int tid  = threadIdx.x;
  const int wv   = tid >> 6;        // wave 0..7 (K=1024 split 8 ways)
  const int lane = tid & 63;
  const int l15  = lane & 15;
  const int quad = lane >> 4;
  const int blk  = blockIdx.x;
  const int g    = blk & 7;         // batch group (likely XCD)
  const int role = blk >> 3;        // 0..31 within group
  const int j0u  = role * UPB;      // first hidden unit owned
  const int m0   = g * 8;           // first batch row of this group

  // ---- 32 weight fragments per wave (128 regs; AGPR-resident) ----
  short8 wfrag[4][NT];
  {
    const ushort* wp = whh_sw + (long)(role * 8 + wv) * 16384 + lane * 8;
    #pragma unroll
    for (int c = 0; c < 4; ++c)
      #pragma unroll
      for (int nt = 0; nt < NT; ++nt)
        wfrag[c][nt] = *(const short8*)(wp + (c * NT + nt) * 512);
  }
  #pragma unroll
  for (int c = 0; c < 4; ++c)
    #pragma unroll
    for (int nt = 0; nt < NT; ++nt)
      asm volatile("" : "+v"(wfrag[c][nt]));

  // ---- cell mapping: threads 0..255 own (batch em 0..7, unit uu 0..31) ----
  const int em = tid >> 5;
  const int uu = tid & 31;
  float bi = 0, bf_ = 0, bg = 0, bo = 0;
  if (tid < 256) {
    bi  = bias[0 * HDIM + j0u + uu];
    bf_ = bias[1 * HDIM + j0u + uu];
    bg  = bias[2 * HDIM + j0u + uu];
    bo  = bias[3 * HDIM + j0u + uu];
  }
  float cst = 0.0f;

  // ---- waves 4-7: x-gate staging mapping (lane4 -> em4, gate g4, 4 units) ----
  const int lane4 = (tid - 256) & 255;     // valid when tid>=256; benign otherwise
  const int em4 = lane4 >> 5;
  const int g4  = (lane4 >> 3) & 3;
  const int u0  = (lane4 & 7) * 4;
  const half_t* xsrc = xproj + (long)(m0 + em4) * ILEN * (4 * HDIM)
                       + g4 * HDIM + j0u + u0;

  // ---- sync: wave wv's chunk c comes from role 4*wv + c ----
  int* const fmine = flags + (g * GBLK + role) * 32;
  const int fidx = (lane < 4) ? (g * GBLK + wv * 4 + lane) : (g * GBLK + role);
  const int* const myfp = flags + fidx * 32;

  // ---- pre-stage x(0) into xbuf slot 0 (ordered by barrier1 of t=0) ----
  if (tid >= 256) {
    ushort4 x0 = *(const ushort4*)xsrc;
    float4 v;
    v.x = (float)__builtin_bit_cast(half_t, (ushort)x0.x);
    v.y = (float)__builtin_bit_cast(half_t, (ushort)x0.y);
    v.z = (float)__builtin_bit_cast(half_t, (ushort)x0.z);
    v.w = (float)__builtin_bit_cast(half_t, (ushort)x0.w);
    *(float4*)(xbuf + 0 * 1024 + em4 * 128 + g4 * 32 + u0) = v;
  }

  for (int t = 0; t < TTOT; ++t) {
    const ushort* __restrict__ hsrc = hbuf + (t & 3) * HSLOT;
    ushort* __restrict__ hdst = hbuf + ((t + 1) & 3) * HSLOT;

    // ---- poll: lanes 0..3 watch this wave's 4 producer roles ----
    for (;;) {
      int v = ldflag<FAST>(myfp);
      if (__all(v >= t)) break;
      __builtin_amdgcn_s_sleep(1);
    }

    // ---- h loads for this wave's K slice (in-asm waitcnt) ----
    const ushort* hb = hsrc + (long)(m0 + (l15 & 7)) * HDIM + wv * 128 + quad * 8;
    short8 ah0, ah1, ah2, ah3;
    ld_h4<FAST>(hb, ah0, ah1, ah2, ah3);

    // ---- waves 4-7: issue x(t+1) load NOW (no wait); completes after
    //      barrier1, hidden under waves 0-3's reduce window ----
    ushort4 xr;
    const bool havex = (tid >= 256) && (t + 1 < ILEN);
    if (havex) {
      const ushort* xp = (const ushort*)(xsrc + (long)(t + 1) * (4 * HDIM));
      asm volatile("global_load_dwordx2 %0, %1, off"
                   : "=&v"(xr) : "v"(xp) : "memory");
    }

    f32x4 acc[NT];
    #pragma unroll
    for (int nt = 0; nt < NT; ++nt)
      #pragma unroll
      for (int r = 0; r < 4; ++r) acc[nt][r] = 0.0f;

    #pragma unroll
    for (int nt = 0; nt < NT; ++nt)
      acc[nt] = __builtin_amdgcn_mfma_f32_16x16x32_bf16(ah0, wfrag[0][nt], acc[nt], 0, 0, 0);
    #pragma unroll
    for (int nt = 0; nt < NT; ++nt)
      acc[nt] = __builtin_amdgcn_mfma_f32_16x16x32_bf16(ah1, wfrag[1][nt], acc[nt], 0, 0, 0);
    #pragma unroll
    for (int nt = 0; nt < NT; ++nt)
      acc[nt] = __builtin_amdgcn_mfma_f32_16x16x32_bf16(ah2, wfrag[2][nt], acc[nt], 0, 0, 0);
    #pragma unroll
    for (int nt = 0; nt < NT; ++nt)
      acc[nt] = __builtin_amdgcn_mfma_f32_16x16x32_bf16(ah3, wfrag[3][nt], acc[nt], 0, 0, 0);

    // ---- partials to LDS (col = n, lane-stride 1 => conflict-free) ----
    if (quad < 2) {
      #pragma unroll
      for (int nt = 0; nt < NT; ++nt)
        #pragma unroll
        for (int r = 0; r < 4; ++r)
          part[(wv * 16 + quad * 4 + r) * PN + nt * 16 + l15] = acc[nt][r];
    }

    // ---- barrier1: RAW (lgkm drain only); waves 4-7 x load stays in
    //      flight. All waves passed polls => all 32 group flags >= t =>
    //      ring slot (t+1)&3 (holding h(t-3)) safe to overwrite. ----
    asm volatile("s_waitcnt lgkmcnt(0)" ::: "memory");
    __builtin_amdgcn_s_barrier();

    ushort h16 = 0;
    if (tid < 256) {
      // x gates from LDS (staged last step by waves 4-7); zeros when padded
      float xi = 0, xf = 0, xg = 0, xo = 0;
      if (t < ILEN) {
        const float* xb = xbuf + (t & 1) * 1024 + em * 128 + uu;
        xi = xb[0]; xf = xb[32]; xg = xb[64]; xo = xb[96];
      }
      float gi = bi + xi, gf = bf_ + xf, gg = bg + xg, go = bo + xo;
      #pragma unroll
      for (int w = 0; w < 8; ++w) {
        const float* pw = part + (w * 16 + em) * PN;
        gi += pw[0 * 32 + uu];
        gf += pw[1 * 32 + uu];
        gg += pw[2 * 32 + uu];
        go += pw[3 * 32 + uu];
      }
      const float si = fast_sigmoid(gi);
      const float sf = fast_sigmoid(gf);
      const float tg = fast_tanh(gg);
      const float so = fast_sigmoid(go);
      cst = sf * cst + si * tg;
      const float h = so * fast_tanh(cst);
      h16 = f2bf(h);
      if constexpr (FAST)
        hdst[(long)(m0 + em) * HDIM + j0u + uu] = h16;      // L2-local (XCD)
      else
        st_h_sys(hdst + (long)(m0 + em) * HDIM + j0u + uu, h16);  // IF
    } else if (havex) {
      // complete x(t+1): only this wave's single load is outstanding
      asm volatile("s_waitcnt vmcnt(0)" ::: "memory");
      float4 v;
      v.x = (float)__builtin_bit_cast(half_t, (ushort)xr.x);
      v.y = (float)__builtin_bit_cast(half_t, (ushort)xr.y);
      v.z = (float)__builtin_bit_cast(half_t, (ushort)xr.z);
      v.w = (float)__builtin_bit_cast(half_t, (ushort)xr.w);
      *(float4*)(xbuf + ((t + 1) & 1) * 1024 + em4 * 128 + g4 * 32 + u0) = v;
    }

    // ---- publish: own h stores complete before flag store ----
    vm_drain();
    __syncthreads();
    if (tid == 0) stflag<FAST>(fmine, t + 1);   // monotonic, no ABA

    // ---- off-critical-path work after publish ----
    if (tid < 256 && t >= ILEN)
      hs_bf[((long)(m0 + em) * TLEN + (t - ILEN)) * HDIM + j0u + uu] = h16;
  }
}

__global__ __launch_bounds__(NTHR, 2) void lstm_kernel(
    const ushort* __restrict__ whh_sw, const half_t* __restrict__ xproj,
    const float* __restrict__ bias,
    ushort* __restrict__ hbuf, ushort* __restrict__ hs_bf,
    int* __restrict__ flags, int* __restrict__ hand)
{
  // ---- group XCD census: fast path only if all 32 blocks share one XCD ----
  int xcd = 0;
  asm volatile("s_getreg_b32 %0, hwreg(HW_REG_XCC_ID)" : "=s"(xcd));
  const int g = blockIdx.x & 7;
  if (threadIdx.x == 0) {
    __hip_atomic_fetch_or(&hand[g * 8], 1 << (xcd & 7),
                          __ATOMIC_RELAXED, __HIP_MEMORY_SCOPE_SYSTEM);
    __hip_atomic_fetch_add(&hand[64 + g * 8], 1,
                           __ATOMIC_RELAXED, __HIP_MEMORY_SCOPE_SYSTEM);
  }
  while (__hip_atomic_load(&hand[64 + g * 8], __ATOMIC_RELAXED,
                           __HIP_MEMORY_SCOPE_SYSTEM) < GBLK)
    __builtin_amdgcn_s_sleep(2);
  const bool fast =
      __popc(__hip_atomic_load(&hand[g * 8], __ATOMIC_RELAXED,
                               __HIP_MEMORY_SCOPE_SYSTEM)) == 1;

  if (fast) lstm_body<true >(whh_sw, xproj, bias, hbuf, hs_bf, flags);
  else      lstm_body<false>(whh_sw, xproj, bias, hbuf, hs_bf, flags);
}

// ---------------- classifier: sigmoid(hs @ clf_w^T + clf_b) ----------------
__global__ __launch_bounds__(256, 1) void clf_kernel(
    const ushort* __restrict__ hs_bf, const ushort* __restrict__ clfw_bf,
    const float* __restrict__ clf_b, float* __restrict__ out)
{
  const int tid = threadIdx.x;
  const int wv = tid >> 6, lane = tid & 63, l15 = lane & 15, quad = lane >> 4;
  const int m0 = blockIdx.x * 64 + wv * 16;   // rows = (b, tt) pairs, 4096 total

  f32x4 acc[8];
  #pragma unroll
  for (int nt = 0; nt < 8; ++nt)
    #pragma unroll
    for (int r = 0; r < 4; ++r) acc[nt][r] = 0.0f;

  for (int kc = 0; kc < HDIM / 32; ++kc) {
    const int k = kc * 32 + quad * 8;
    short8 a = *(const short8*)(hs_bf + (long)(m0 + l15) * HDIM + k);
    #pragma unroll
    for (int nt = 0; nt < 8; ++nt) {
      short8 b = *(const short8*)(clfw_bf + (long)(nt * 16 + l15) * HDIM + k);
      acc[nt] = __builtin_amdgcn_mfma_f32_16x16x32_bf16(a, b, acc[nt], 0, 0, 0);
    }
  }
  #pragma unroll
  for (int nt = 0; nt < 8; ++nt) {
    const int n = nt * 16 + l15;
    const float bn = clf_b[n];
    #pragma unroll
    for (int r = 0; r < 4; ++r) {
      const int m = m0 + quad * 4 + r;
      out[(long)m * ODIM + n] = fast_sigmoid(acc[nt][r] + bn);
    }
  }
}

// ---------------- launch ----------------
extern "C" void kernel_launch(void* const* d_in, const int* in_sizes, int n_in,
                              void* d_out, int out_size, void* d_ws, size_t ws_size,
                              hipStream_t stream) {
  const float* inp   = (const float*)d_in[0];
  // d_in[1] = tlen scalar (fixed = 64 for this problem)
  const float* w_ih  = (const float*)d_in[2];
  const float* w_hh  = (const float*)d_in[3];
  const float* bias  = (const float*)d_in[4];
  const float* clf_w = (const float*)d_in[5];
  const float* clf_b = (const float*)d_in[6];
  float* out = (float*)d_out;

  // ws layout (bytes): total ~172.8 MB
  char* ws = (char*)d_ws;
  ushort* inp_bf  = (ushort*)(ws + 0);          // 16,777,216
  ushort* wih_bf  = (ushort*)(ws + 16777216);   //  4,194,304
  ushort* whh_sw  = (ushort*)(ws + 20971520);   //  8,388,608 (swizzled w_hh)
  ushort* clfw_bf = (ushort*)(ws + 29360128);   //    262,144
  ushort* hbuf    = (ushort*)(ws + 29622272);   //    524,288 (4-slot h ring)
  ushort* hs_bf   = (ushort*)(ws + 30146560);   //  8,388,608 (last-64-step h)
  int*    bar     = (int*)   (ws + 38535168);   //     32,768 (per-block flags)
  int*    hand    = (int*)   (ws + 38567936);   //      1,024 (XCD census)
  half_t* xproj   = (half_t*)(ws + 38568960);   // 134,217,728 (fp16 x-projection)

  prep_kernel<<<4096, 256, 0, stream>>>(inp, clf_w, w_ih, w_hh,
                                        inp_bf, clfw_bf, wih_bf, whh_sw,
                                        hbuf, bar, hand);
  xproj_kernel<<<4096, 256, 0, stream>>>(inp_bf, wih_bf, xproj);
  lstm_kernel<<<NBLK, NTHR, (8 * 16 * PN + XBUFF) * 4, stream>>>(
      whh_sw, xproj, bias, hbuf, hs_bf, bar, hand);
  clf_kernel<<<64, 256, 0, stream>>>(hs_bf, clfw_bf, clf_b, out);
}